// Round 1
// 346.453 us; speedup vs baseline: 1.0257x; 1.0257x over previous
//
#include <hip/hip_runtime.h>
#include <math.h>

// ---------------- model constants (double-precision derivation, f32 use) ----
static constexpr double dTS    = 1.0 / 44100.0;
static constexpr double dCM    = 12.5e-12;
static constexpr double dK     = dTS / dCM;              // Ts/CM
static constexpr double dGKF   = 19.8e-9;
static constexpr double dGKS   = 19.8e-9;
static constexpr double dEKF   = -71e-3;
static constexpr double dEKS   = -78e-3;
static constexpr double dEP    = 90e-3;
static constexpr double dGMET  = 30e-9;
static constexpr double dSCALE = 5.623413251903491e-06;  // 10^(-105/20)
static constexpr double dX0    = 20e-9;
static constexpr double dS0    = 16e-9;
static constexpr double dS1    = 35e-9;
static constexpr double dL2E   = 1.4426950408889634;     // log2(e)

// G = GMET / (1 + e^{z/S1}(1+e^{z/S0})),  z = X0 - SCALE*x
//   = GMET / (1 + 2^{K1*x+C1} + 2^{K2*x+C2})   (exp2-fused, one fma per exp)
static constexpr float F_K1   = (float)(-dSCALE / dS1 * dL2E);
static constexpr float F_C1   = (float)( dX0    / dS1 * dL2E);
static constexpr float F_K2   = (float)(-dSCALE * (1.0/dS1 + 1.0/dS0) * dL2E);
static constexpr float F_C2   = (float)( dX0    * (1.0/dS1 + 1.0/dS0) * dL2E);
static constexpr float F_ANOG = (float)(1.0 - (dGKF + dGKS) * dK);
static constexpr float F_GMK  = (float)(dGMET * dK);
static constexpr float F_EP   = (float)dEP;
static constexpr float F_C0   = (float)(dEP + (dGKF*(dEKF-dEP) + dGKS*(dEKS-dEP)) * dK);

constexpr int T_LEN = 131072;   // time samples per lane
constexpr int CHUNK = 8192;     // output samples per block
constexpr int WARM  = 256;      // a<=0.9282 -> a^256 ~ 5.7e-9: converged (<3e-10 V err)
constexpr int SPT   = 32;       // main samples per thread: 256*32 = 8192
constexpr int NTH   = 256;

typedef float v4f __attribute__((ext_vector_type(4)));

// MET conductance -> recurrence coefficient a = 1 - (G+GKF+GKS)*Ts/CM
__device__ __forceinline__ float coef(float xv) {
    float e1  = __builtin_amdgcn_exp2f(fmaf(F_K1, xv, F_C1));
    float e2  = __builtin_amdgcn_exp2f(fmaf(F_K2, xv, F_C2));
    float den = 1.0f + e1 + e2;                   // inf-safe -> rcp = 0
    return fmaf(-F_GMK, __builtin_amdgcn_rcpf(den), F_ANOG);
}

__global__ __launch_bounds__(NTH, 5) void ihc_kernel(const float* __restrict__ x,
                                                     float* __restrict__ out,
                                                     float vpre) {
    const int c = blockIdx.x;                     // chunk index 0..15
    const int l = blockIdx.y;                     // lane index 0..399
    const int t = threadIdx.x;
    const long lbase = (long)l * T_LEN;
    const float* xp  = x + lbase + (long)c * CHUNK;
    float* opc       = out + lbase + (long)c * CHUNK;

    // 32 KB exactly -> 5 blocks/CU. Used for: scan scratch (floats 0..15,
    // aliased, dead by Phase D) then swizzled output staging.
    __shared__ float lbuf[CHUNK];
    float4* lb4 = reinterpret_cast<float4*>(lbuf);

    // ---- main input: 8 aligned float4 per thread (contiguous 32 floats).
    // 128B-stride pattern; every 64B line fully consumed within the 8-load
    // window -> L1 merges, HBM traffic is exact.
    float4 q[8];
    const float4* qp = reinterpret_cast<const float4*>(xp + t * SPT);
#pragma unroll
    for (int j = 0; j < 8; ++j) q[j] = qp[j];

    // ---- warm-up: ONE sample per thread (256 total), identity for chunk 0
    float aw, bw;
    {
        const int woff = (c == 0) ? 0 : -WARM;    // c==0: dummy in-bounds read
        float wx = xp[t + woff];
        aw = coef(wx);
        bw = fmaf(-F_EP, aw, F_C0);
        if (c == 0) { aw = 1.0f; bw = 0.0f; }
    }

    // ---- pass 1: per-element coefficient + local affine composition (A,B)
    // maskless: all main indices are in [0, T_LEN)
    float A = 1.0f, B = 0.0f;
#pragma unroll
    for (int j = 0; j < 8; ++j) {
        float ev[4] = {q[j].x, q[j].y, q[j].z, q[j].w};
#pragma unroll
        for (int i = 0; i < 4; ++i) {
            float a = coef(ev[i]);
            float b = fmaf(-F_EP, a, F_C0);
            B = fmaf(a, B, b);
            A = A * a;
            ev[i] = a;
        }
        q[j] = make_float4(ev[0], ev[1], ev[2], ev[3]);
    }

    // ---- interleaved intra-wave inclusive scans (warm + main share steps)
    const int lane = t & 63;
    const int w    = t >> 6;
#pragma unroll
    for (int d = 1; d < 64; d <<= 1) {
        float pa  = __shfl_up(A,  d, 64);
        float pb  = __shfl_up(B,  d, 64);
        float pwa = __shfl_up(aw, d, 64);
        float pwb = __shfl_up(bw, d, 64);
        if (lane >= d) {
            B  = fmaf(A,  pb,  B);  A  *= pa;
            bw = fmaf(aw, pwb, bw); aw *= pwa;
        }
    }

    // wave totals -> scratch (first touch of lbuf; no earlier readers)
    if (lane == 63) {
        lbuf[w]      = aw;  lbuf[4 + w]  = bw;     // warm wave totals
        lbuf[8 + w]  = A;   lbuf[12 + w] = B;      // main wave totals
    }
    __syncthreads();

    // warm total = compose all 4 wave segments (time order)
    float wA = 1.0f, wB = 0.0f;
#pragma unroll
    for (int i = 0; i < 4; ++i) { wB = fmaf(lbuf[i], wB, lbuf[4 + i]); wA *= lbuf[i]; }
    // main exclusive prefix across waves
    float eA = 1.0f, eB = 0.0f;
    for (int i = 0; i < w; ++i) { eB = fmaf(lbuf[8 + i], eB, lbuf[12 + i]); eA *= lbuf[8 + i]; }
    float sa = __shfl_up(A, 1, 64);
    float sb = __shfl_up(B, 1, 64);
    if (lane == 0) { sa = 1.0f; sb = 0.0f; }

    float vw = fmaf(wA, vpre, wB);                // state after warm-up
    float u  = fmaf(eA, vw, eB);                  // state at wave start
    float v  = fmaf(sa, u, sb);                   // state at this thread's segment
    __syncthreads();                              // scratch reads before D overwrites

    // ---- Phase D: replay recurrence, XOR-swizzled LDS writes
    // logical f4 group G = t*8+j stored at G ^ ((G>>3)&7) = 8t + (j^(t&7)):
    // spreads the stride-128B pattern across all banks (conflict-free).
    const int s = t & 7;
#pragma unroll
    for (int j = 0; j < 8; ++j) {
        float ev[4] = {q[j].x, q[j].y, q[j].z, q[j].w};
        float ov[4];
#pragma unroll
        for (int i = 0; i < 4; ++i) {
            float a = ev[i];
            float b = fmaf(-F_EP, a, F_C0);
            v = fmaf(a, v, b);
            ov[i] = v - vpre;
        }
        lb4[t * 8 + (j ^ s)] = make_float4(ov[0], ov[1], ov[2], ov[3]);
    }
    __syncthreads();

    // ---- Phase E: swizzled LDS read -> coalesced nontemporal global stores
#pragma unroll
    for (int j = 0; j < 8; ++j) {
        int g  = t + NTH * j;                     // logical f4 group 0..2047
        int gp = g ^ ((g >> 3) & 7);              // same involution as D
        float4 o = lb4[gp];
        v4f ov = { o.x, o.y, o.z, o.w };
        __builtin_nontemporal_store(ov, reinterpret_cast<v4f*>(opc + 4 * g));
    }
}

// 50 ms pre-charge relaxation, f32 forward Euler (matches reference dtype)
static float compute_vpre() {
    const float TsCM = (float)dK;
    float v = -57.03e-3f;
    for (int i = 0; i < 2205; ++i) {
        float Imet = 3.3514e-9f * (v - 0.09f);
        float Ik   = 19.8e-9f   * (v + 0.071f);
        float Is   = 19.8e-9f   * (v + 0.078f);
        v = v - (Imet + Ik + Is) * TsCM;
    }
    return v;
}

extern "C" void kernel_launch(void* const* d_in, const int* in_sizes, int n_in,
                              void* d_out, int out_size, void* d_ws, size_t ws_size,
                              hipStream_t stream) {
    const float* x = (const float*)d_in[0];
    float* out = (float*)d_out;
    const int lanes = in_sizes[0] / T_LEN;        // B*F = 400
    const int nchunks = T_LEN / CHUNK;            // 16
    float vpre = compute_vpre();                  // deterministic scalar, graph-safe
    dim3 grid(nchunks, lanes);
    hipLaunchKernelGGL(ihc_kernel, grid, dim3(NTH), 0, stream, x, out, vpre);
}